// Round 4
// baseline (75.560 us; speedup 1.0000x reference)
//
#include <hip/hip_runtime.h>

// PhaseLinear: out[b,o] = sum_c coef[b,c] * (sum_i in[b,i]*W[c,o,i] + bias[c,o])
// Dtype model (round 3 evidence): ALL inputs float32, output float32.
// f32 inputs are converted to bf16 (RNE) in-register during LDS staging,
// MFMA bf16 accumulate f32, fused 4-way control-point blend epilogue, f32 out.
// GEMM view: A(1024x512) . W^T(2048x512).

#define BATCH 1024
#define IN_F  512
#define OUT_F 512

constexpr int BM = 32;                       // batch rows per block
constexpr int BO = 64;                       // out features per block (x4 ctrl pts)
constexpr int BK = 32;                       // K per stage
constexpr int KITERS = IN_F / BK;            // 16
constexpr int A_ELEMS = BM * BK;             // 1024 elems
constexpr int TILE_ELEMS = (BM + 4 * BO) * BK;  // 9216 elems per stage
constexpr int NVEC = TILE_ELEMS / 8;         // 1152 8-elem slots per stage

typedef unsigned short u16;
typedef u16    u16x8  __attribute__((ext_vector_type(8)));
typedef __bf16 bf16x8 __attribute__((ext_vector_type(8)));
typedef float  f32x4  __attribute__((ext_vector_type(4)));

__device__ __forceinline__ u16 f2bits(float f) {   // f32 -> bf16 bits, RNE
  union { float f; unsigned int u; } v; v.f = f;
  unsigned int u = v.u;
  unsigned int r = u + 0x7fffu + ((u >> 16) & 1u);
  return (u16)(r >> 16);
}

__global__ __launch_bounds__(256)
void PhaseLinear_kernel(const float* __restrict__ inp, const float* __restrict__ ph,
                        const float* __restrict__ wts, const float* __restrict__ bia,
                        float* __restrict__ outp) {
  // double-buffered bf16 staging tile: [A (32x32) | W (256x32)] rows k-contig
  __shared__ alignas(16) u16 sT[2][TILE_ELEMS];   // 2 x 18 KB
  __shared__ float sCoef[BM][4];

  const int tid = threadIdx.x;
  const int wv  = tid >> 6;        // wave 0..3 -> 16-out slice
  const int l   = tid & 63;
  const int o0  = blockIdx.x * BO;
  const int b0  = blockIdx.y * BM;

  // --- spline coefficients (replicates reference tt=[1,t^2,t^3,0] bug) ---
  if (tid < BM) {
    const float PI = 3.14159265358979323846f;
    float p  = ph[b0 + tid];
    float t  = (p < 1.5f * PI) ? (p / (1.5f * PI)) : ((p - 0.5f * PI) / (1.5f * PI));
    float t2 = t * t, t3 = t2 * t;
    sCoef[tid][0] = t3 - 0.5f * t2;        // tt @ (0.5*CATMULL_ROM_BASIS)
    sCoef[tid][1] = 1.0f - 2.5f * t3;
    sCoef[tid][2] = 0.5f * t2 + 2.0f * t3;
    sCoef[tid][3] = -0.5f * t3;
  }

  // --- per-thread staging slots: slot v covers LDS elems [v*8, v*8+8) ---
  // thread t owns v = t, t+256, t+512, t+768 (+ t+1024 if t<128)
  const int nv = (tid < NVEC - 1024) ? 5 : 4;
  const float* src[5];
  int loff[5];
#pragma unroll
  for (int j = 0; j < 5; ++j) {
    int v = tid + j * 256;
    if (v >= NVEC) { src[j] = inp; loff[j] = 0; continue; }   // unused slot
    int e = v * 8;
    loff[j] = e;
    if (e < A_ELEMS) {                       // A region: input rows
      int row = e >> 5, col = e & 31;
      src[j] = inp + (size_t)(b0 + row) * IN_F + col;
    } else {                                 // W region: (c, o) rows
      int ep = e - A_ELEMS;
      int r = ep >> 5, col = ep & 31;        // r in 0..255
      int c = r >> 6, oo = r & 63;
      src[j] = wts + ((size_t)c * OUT_F + o0 + oo) * IN_F + col;
    }
  }

  // prefetch K-step 0 (f32) into registers
  f32x4 regs[5][2];
#pragma unroll
  for (int j = 0; j < 5; ++j)
    if (j < nv) {
      regs[j][0] = *(const f32x4*)(src[j]);
      regs[j][1] = *(const f32x4*)(src[j] + 4);
    }

  f32x4 acc[2][4];
#pragma unroll
  for (int m = 0; m < 2; ++m)
#pragma unroll
    for (int c = 0; c < 4; ++c) acc[m][c] = (f32x4){0.f, 0.f, 0.f, 0.f};

  const int q = l >> 4;    // k-quad
  const int n = l & 15;    // M index (A) / N index (B) / col of C

  for (int kk = 0; kk < KITERS; ++kk) {
    const int bsel = kk & 1;
    u16* buf = &sT[bsel][0];
    // convert f32 -> bf16 (RNE) and store to LDS
#pragma unroll
    for (int j = 0; j < 5; ++j)
      if (j < nv) {
        u16x8 pk;
#pragma unroll
        for (int x = 0; x < 4; ++x) {
          pk[x]     = f2bits(regs[j][0][x]);
          pk[x + 4] = f2bits(regs[j][1][x]);
        }
        *(u16x8*)(buf + loff[j]) = pk;
      }
    // issue next step's global loads (latency hidden behind barrier+MFMA)
    if (kk + 1 < KITERS) {
#pragma unroll
      for (int j = 0; j < 5; ++j)
        if (j < nv) {
          regs[j][0] = *(const f32x4*)(src[j] + (kk + 1) * BK);
          regs[j][1] = *(const f32x4*)(src[j] + (kk + 1) * BK + 4);
        }
    }
    __syncthreads();                         // buf fully written by all waves
    const u16* pA = buf;                     // 32 rows x 32
    const u16* pW = buf + A_ELEMS;           // 256 rows x 32
    bf16x8 a0 = *(const bf16x8*)(pA + (n)      * BK + q * 8);
    bf16x8 a1 = *(const bf16x8*)(pA + (n + 16) * BK + q * 8);
#pragma unroll
    for (int c = 0; c < 4; ++c) {
      bf16x8 wf = *(const bf16x8*)(pW + (c * 64 + wv * 16 + n) * BK + q * 8);
      acc[0][c] = __builtin_amdgcn_mfma_f32_16x16x32_bf16(a0, wf, acc[0][c], 0, 0, 0);
      acc[1][c] = __builtin_amdgcn_mfma_f32_16x16x32_bf16(a1, wf, acc[1][c], 0, 0, 0);
    }
    // no trailing barrier: next iter writes the OTHER buffer; passing the
    // next barrier implies every wave drained these ds_reads (lgkmcnt(0))
  }

  // --- epilogue: blend 4 control points + bias, f32 store ---
  // C/D layout (m89/m91 verified): col = l&15, row = (l>>4)*4 + reg
  const int o = o0 + wv * 16 + n;
  float bs[4];
#pragma unroll
  for (int c = 0; c < 4; ++c) bs[c] = bia[c * OUT_F + o];

#pragma unroll
  for (int mf = 0; mf < 2; ++mf) {
#pragma unroll
    for (int r = 0; r < 4; ++r) {
      const int bl = mf * 16 + q * 4 + r;
      float v = 0.f;
#pragma unroll
      for (int c = 0; c < 4; ++c)
        v += sCoef[bl][c] * (acc[mf][c][r] + bs[c]);
      outp[(size_t)(b0 + bl) * OUT_F + o] = v;
    }
  }
}

extern "C" void kernel_launch(void* const* d_in, const int* in_sizes, int n_in,
                              void* d_out, int out_size, void* d_ws, size_t ws_size,
                              hipStream_t stream) {
  const float* inp = (const float*)d_in[0];   // input  (1024, 512) f32
  const float* ph  = (const float*)d_in[1];   // phase  (1024,)     f32
  const float* wts = (const float*)d_in[2];   // weights(4,512,512) f32
  const float* bia = (const float*)d_in[3];   // biases (4,512)     f32
  float* outp = (float*)d_out;                // out    (1024,512)  f32

  dim3 grid(OUT_F / BO, BATCH / BM);          // (8, 32) = 256 blocks, 1/CU
  PhaseLinear_kernel<<<grid, 256, 0, stream>>>(inp, ph, wts, bia, outp);
}